// Round 1
// 93.979 us; speedup vs baseline: 1.0041x; 1.0041x over previous
//
#include <hip/hip_runtime.h>
#include <math.h>

#define DEV __device__ __forceinline__

// ---------------------------------------------------------------------------
// Cross-lane xor within 32-lane groups. Masks 1,2,3 -> DPP quad_perm,
// mask 8 -> DPP row_ror:8 (16-lane row), others (4,6,9,12,16) -> ds_swizzle
// bit-mode. Mask 32 crossings use ds_bpermute (wave-wide).
// ---------------------------------------------------------------------------
template<int M>
DEV float lxor(float x) {
    const int i = __builtin_bit_cast(int, x);
    int r;
    if constexpr (M == 1)      r = __builtin_amdgcn_update_dpp(i, i, 0xB1, 0xF, 0xF, false);
    else if constexpr (M == 2) r = __builtin_amdgcn_update_dpp(i, i, 0x4E, 0xF, 0xF, false);
    else if constexpr (M == 3) r = __builtin_amdgcn_update_dpp(i, i, 0x1B, 0xF, 0xF, false);
    else if constexpr (M == 8) r = __builtin_amdgcn_update_dpp(i, i, 0x128, 0xF, 0xF, false);
    else                       r = __builtin_amdgcn_ds_swizzle(i, (M << 10) | 0x1F);
    return __builtin_bit_cast(float, r);
}
template<int M> DEV float2 lxor2(float2 v) {
    return make_float2(lxor<M>(v.x), lxor<M>(v.y));
}
DEV float bpermf(int addr, float x) {
    return __builtin_bit_cast(float,
        __builtin_amdgcn_ds_bpermute(addr, __builtin_bit_cast(int, x)));
}
DEV float2 bperm2(int addr, float2 v) {
    return make_float2(bpermf(addr, v.x), bpermf(addr, v.y));
}
DEV float red16(float x) {
    x += lxor<8>(x); x += lxor<4>(x); x += lxor<2>(x); x += lxor<1>(x);
    return x;
}
DEV float red32(float x) {
    x += lxor<16>(x);
    return red16(x);
}
DEV float red64(float x, int a32) {
    x += bpermf(a32, x);
    return red32(x);
}

// ---------------------------------------------------------------------------
// 16-amp ring-sim helpers: 1 amp/lane within a 16-lane group; wire w <-> mask 8>>w.
// SU(2): U = [[u00, u01], [-conj(u01), conj(u00)]].
// ---------------------------------------------------------------------------
template<int LM>
DEV void sgate(float2& v, int l16, float2 u00, float2 u01) {
    const bool hi = (l16 & LM) != 0;
    const float e00x = u00.x, e00y = hi ? -u00.y : u00.y;
    const float e01x = hi ? -u01.x : u01.x, e01y = u01.y;
    const float2 p = lxor2<LM>(v);
    v = make_float2(e00x*v.x - e00y*v.y + e01x*p.x - e01y*p.y,
                    e00x*v.y + e00y*v.x + e01x*p.y + e01y*p.x);
}
template<int LM>
DEV void sgate4(float2& v, int l16, float4 g) {
    sgate<LM>(v, l16, make_float2(g.x, g.y), make_float2(g.z, g.w));
}
template<int CL, int LM>
DEV void scrx(float2& v, int l16, float2 cs) {
    const bool hi = (l16 & CL) != 0;
    const float c = hi ? cs.x : 1.f, sn = hi ? cs.y : 0.f;
    const float2 p = lxor2<LM>(v);
    v = make_float2(c*v.x + sn*p.y, c*v.y - sn*p.x);
}
template<int LM2>
DEV void sixx(float2& v, float2 cs) {
    const float2 p = lxor2<LM2>(v);
    v = make_float2(cs.x*v.x + cs.y*p.y, cs.x*v.y - cs.y*p.x);
}
template<int LM>
DEV void srx(float2& v, float c, float sn) {
    const float2 p = lxor2<LM>(v);
    v = make_float2(c*v.x + sn*p.y, c*v.y - sn*p.x);
}
template<int CL, int LM>
DEV void scnot(float2& v, int l16) {
    const float2 p = lxor2<LM>(v);
    const bool hi = (l16 & CL) != 0;
    v = hi ? p : v;
}

// ---------------------------------------------------------------------------
// Full 256-amp state: 4 float2/lane, 64 lanes/element (1 element = 1 wave).
// Wire map: w0->L16, w1->L8, w2->R2, w3->R1, w4->L32, w5->L4, w6->L2, w7->L1.
// ---------------------------------------------------------------------------
template<int CL, int LM>
DEV void xcrx_ll(float2 (&s)[4], int ln, float2 cs) {   // ctrl lane, tgt lane
    const bool hi = (ln & CL) != 0;
    const float c = hi ? cs.x : 1.f, sn = hi ? cs.y : 0.f;
#pragma unroll
    for (int r = 0; r < 4; r++) {
        const float2 p = lxor2<LM>(s[r]);
        const float2 a = s[r];
        s[r] = make_float2(c*a.x + sn*p.y, c*a.y - sn*p.x);
    }
}
template<int CL>
DEV void xcrx_l32(float2 (&s)[4], int ln, int a32, float2 cs) {  // ctrl lane, tgt L32
    const bool hi = (ln & CL) != 0;
    const float c = hi ? cs.x : 1.f, sn = hi ? cs.y : 0.f;
#pragma unroll
    for (int r = 0; r < 4; r++) {
        const float2 p = bperm2(a32, s[r]);
        const float2 a = s[r];
        s[r] = make_float2(c*a.x + sn*p.y, c*a.y - sn*p.x);
    }
}
template<int CM, int LM>
DEV void xcrx_rl(float2 (&s)[4], float2 cs) {            // ctrl reg, tgt lane
#pragma unroll
    for (int r = 0; r < 4; r++) {
        if (!(r & CM)) continue;
        const float2 p = lxor2<LM>(s[r]);
        const float2 a = s[r];
        s[r] = make_float2(cs.x*a.x + cs.y*p.y, cs.x*a.y - cs.y*p.x);
    }
}
template<int CM>
DEV void xcrx_r32(float2 (&s)[4], int a32, float2 cs) {  // ctrl reg, tgt L32
#pragma unroll
    for (int r = 0; r < 4; r++) {
        if (!(r & CM)) continue;
        const float2 p = bperm2(a32, s[r]);
        const float2 a = s[r];
        s[r] = make_float2(cs.x*a.x + cs.y*p.y, cs.x*a.y - cs.y*p.x);
    }
}
template<int CL, int RM>
DEV void xcrx_lr(float2 (&s)[4], int ln, float2 cs) {    // ctrl lane, tgt reg
    const bool hi = (ln & CL) != 0;
    const float c = hi ? cs.x : 1.f, sn = hi ? cs.y : 0.f;
#pragma unroll
    for (int r = 0; r < 4; r++) {
        if (r & RM) continue;
        const int r1 = r | RM;
        const float2 a = s[r], b = s[r1];
        s[r]  = make_float2(c*a.x + sn*b.y, c*a.y - sn*b.x);
        s[r1] = make_float2(c*b.x + sn*a.y, c*b.y - sn*a.x);
    }
}

// Heisenberg measurement of A = U^dag P U on reg wire RM (pairs counted once).
template<int RM>
DEV void measRR(const float2 (&s)[4], const float (&n2)[4],
                float4 mz, float2 bx, float& z, float& x) {
    float zz = 0.f, xx = 0.f;
#pragma unroll
    for (int r = 0; r < 4; r++) {
        if (r & RM) continue;
        const int r1 = r | RM;
        const float nd  = n2[r] - n2[r1];
        const float dre = s[r].x*s[r1].x + s[r].y*s[r1].y;
        const float dim = s[r].x*s[r1].y - s[r].y*s[r1].x;
        zz += mz.x*nd + mz.y*dre - mz.z*dim;
        xx += mz.w*nd + bx.x*dre - bx.y*dim;
    }
    z = zz; x = xx;
}
// Lane-wire measurement (pairs counted twice across lanes -> 0.5 factors,
// antisymmetric dim handled by per-lane sign f). Proven pattern from measL16.
template<int LM>
DEV void measLn(const float2 (&s)[4], const float (&n2)[4], int ln,
                float4 mz, float2 bx, float& z, float& x) {
    const float f = (ln & LM) ? -1.f : 1.f;
    float zz = 0.f, xx = 0.f;
#pragma unroll
    for (int r = 0; r < 4; r++) {
        const float2 p = lxor2<LM>(s[r]);
        const float tre = s[r].x*p.x + s[r].y*p.y;
        const float ftim = f * (s[r].x*p.y - s[r].y*p.x);
        const float fn = f * n2[r];
        zz += mz.x*fn + 0.5f*(mz.y*tre - mz.z*ftim);
        xx += mz.w*fn + 0.5f*(bx.x*tre - bx.y*ftim);
    }
    z = zz; x = xx;
}

// Fuse rot-layer SU(2) g with preceding RX(ang): U' = M * RX(ang)
DEV void fuse_rx(float4 g, float ang, float2& u00, float2& u01) {
    float s_, c_;
    __sincosf(0.5f * ang, &s_, &c_);
    u00 = make_float2(g.x*c_ + g.w*s_, g.y*c_ - g.z*s_);
    u01 = make_float2(g.y*s_ + g.z*c_, -g.x*s_ + g.w*c_);
}

// ---------------------------------------------------------------------------
__global__ __launch_bounds__(256, 4) void qa_kernel(
    const float* __restrict__ x_text, const float* __restrict__ x_image,
    const float* __restrict__ W_text, const float* __restrict__ b_text,
    const float* __restrict__ W_image, const float* __restrict__ b_image,
    const float* __restrict__ wq_rot, const float* __restrict__ wq_crx,
    const float* __restrict__ wk_rot, const float* __restrict__ wk_crx,
    const float* __restrict__ wv_rot, const float* __restrict__ wv_crx,
    const float* __restrict__ wc_rot, const float* __restrict__ wc_crx,
    const float* __restrict__ wc_crx2, const float* __restrict__ gates,
    float* __restrict__ out, int B)
{
    // sG fused SU(2): 0-3 qL1, 4-7 qL2, 8-11 kL1, 12-15 kL2, 16-19 final(wc),
    // 20-23 vL1, 24-27 vL2.
    __shared__ float4 sG[28];
    // sCS (cos,sin of t/2): 0-7 wq_crx, 8-15 wk_crx, 16-23 wc_crx,
    // 24-31 wc_crx2, 32-39 wv_crx.
    __shared__ float2 sCS[40];
    __shared__ float4 sWT[192];   // W rows transposed
    __shared__ float4 sMZ[4];     // (az, bz2re, bz2im, ax) per measured wire
    __shared__ float2 sBX[4];     // (bx2re, bx2im)
    __shared__ float  sB[8];      // b_text, b_image
    __shared__ __align__(16) float2 sQK[4][32];  // per element: q[0..15], k[16..31]

    const int tid = threadIdx.x;
    if (tid < 192) {
        const float* W = (tid < 96) ? W_text : W_image;
        const int idx = (tid < 96) ? tid : tid - 96;
        sWT[tid] = make_float4(W[idx], W[96 + idx], W[192 + idx], W[288 + idx]);
    }
    if (tid < 28) {
        const float* srcs[7] = {wq_rot, wq_rot + 12, wk_rot, wk_rot + 12,
                                wc_rot, wv_rot, wv_rot + 12};
        const float* p = srcs[tid >> 2] + 3 * (tid & 3);
        const float a = p[0], bb = p[1], c = p[2];
        float sh, ch, sd, cd, sb, cb;
        __sincosf(0.5f * (a + c), &sh, &ch);
        __sincosf(0.5f * (a - c), &sd, &cd);
        __sincosf(0.5f * bb, &sb, &cb);
        const float4 g = make_float4(cb * ch, -cb * sh, sb * sd, -sb * cd);
        sG[tid] = g;
        if (tid >= 16 && tid < 20) {  // Heisenberg ops for the final rot layer
            const int w = tid - 16;
            const float2 u00 = make_float2(g.x, g.y), u01 = make_float2(g.z, g.w);
            const float az = u00.x*u00.x + u00.y*u00.y - u01.x*u01.x - u01.y*u01.y;
            sMZ[w] = make_float4(az,
                                 4.f*(u00.x*u01.x + u00.y*u01.y),
                                 4.f*(u00.x*u01.y - u00.y*u01.x),
                                 -2.f*(u00.x*u01.x - u00.y*u01.y));
            sBX[w] = make_float2(
                2.f*(u00.x*u00.x - u00.y*u00.y - u01.x*u01.x + u01.y*u01.y),
                -4.f*(u00.x*u00.y + u01.x*u01.y));
        }
    }
    if (tid < 40) {
        const float* srcs[5] = {wq_crx, wk_crx, wc_crx, wc_crx2, wv_crx};
        const float t = srcs[tid >> 3][tid & 7];
        float s_, c_;
        __sincosf(0.5f * t, &s_, &c_);
        sCS[tid] = make_float2(c_, s_);
    }
    if (tid < 8) sB[tid] = (tid < 4) ? b_text[tid] : b_image[tid - 4];
    __syncthreads();

    const int ln   = tid & 63;        // element = one full wave
    const int l16  = ln & 15;
    const int l32  = ln & 31;
    const int half = ln >> 5;         // 0: q-projection lanes, 1: k-projection
    const int g    = ln >> 4;         // 0:q-sim 1:q-dup 2:k-sim 3:v-sim
    const int elem = tid >> 6;
    const int b    = blockIdx.x * 4 + elem;
    if (b >= B) return;

    // ---- projections: lanes 0-31 -> xq, lanes 32-63 -> xk ------------------
    const float* xsrc = (half ? x_image : x_text) + (size_t)b * 96;
    const float4* wbase = sWT + 96 * half;
    float acc[4] = {0.f, 0.f, 0.f, 0.f};
#pragma unroll
    for (int kk = 0; kk < 3; kk++) {
        const int idx = l32 + 32 * kk;
        const float v = xsrc[idx];
        const float4 w = wbase[idx];
        acc[0] += v * w.x; acc[1] += v * w.y; acc[2] += v * w.z; acc[3] += v * w.w;
    }
    float xv[4];
#pragma unroll
    for (int j = 0; j < 4; j++) xv[j] = red32(acc[j]) + sB[4 * half + j];

    // ---- ring sims: q, (q-dup), k, v run concurrently in 16-lane groups ----
    const int gb = (g < 2) ? 0 : (g == 2 ? 8 : 20);
    const int cb = (g < 2) ? 0 : (g == 2 ? 8 : 32);
    float2 A = make_float2((l16 == 0) ? 1.f : 0.f, 0.f);
    {
        float2 u00, u01;
        fuse_rx(sG[gb + 0], xv[0], u00, u01); sgate<8>(A, l16, u00, u01);
        fuse_rx(sG[gb + 1], xv[1], u00, u01); sgate<4>(A, l16, u00, u01);
        fuse_rx(sG[gb + 2], xv[2], u00, u01); sgate<2>(A, l16, u00, u01);
        fuse_rx(sG[gb + 3], xv[3], u00, u01); sgate<1>(A, l16, u00, u01);
    }
    scrx<8, 4>(A, l16, sCS[cb + 0]);
    scrx<4, 2>(A, l16, sCS[cb + 1]);
    scrx<2, 1>(A, l16, sCS[cb + 2]);
    scrx<1, 8>(A, l16, sCS[cb + 3]);
    sixx<12>(A, sCS[cb + 4]);
    sixx<6>(A, sCS[cb + 5]);
    sixx<3>(A, sCS[cb + 6]);
    sixx<9>(A, sCS[cb + 7]);
    sgate4<8>(A, l16, sG[gb + 4]);
    sgate4<4>(A, l16, sG[gb + 5]);
    sgate4<2>(A, l16, sG[gb + 6]);
    sgate4<1>(A, l16, sG[gb + 7]);
    // A of group 3 lanes (v-state) stays live across the cross section.

    // ---- outer product |q> (x) |k| -> 4 regs/lane over 64 lanes ------------
    // Same-wave LDS round trip (element == wave; LDS ops in-order per wave).
    if (!(g & 1)) sQK[elem][(g ? 16 : 0) + l16] = A;
    asm volatile("" ::: "memory");  // keep writes before reads
    const int kidx = ((ln >> 5) & 1) * 8 + (ln & 7);        // L32*8+L4*4+L2*2+L1
    const int qb   = ((ln >> 4) & 1) * 8 + ((ln >> 3) & 1) * 4;  // L16*8+L8*4
    const float2 kk2 = sQK[elem][16 + kidx];
    const float4* qrow = reinterpret_cast<const float4*>(&sQK[elem][qb]);
    float2 s[4];
    {
        const float4 t0 = qrow[0], t1 = qrow[1];
        s[0] = make_float2(t0.x*kk2.x - t0.y*kk2.y, t0.x*kk2.y + t0.y*kk2.x);
        s[1] = make_float2(t0.z*kk2.x - t0.w*kk2.y, t0.z*kk2.y + t0.w*kk2.x);
        s[2] = make_float2(t1.x*kk2.x - t1.y*kk2.y, t1.x*kk2.y + t1.y*kk2.x);
        s[3] = make_float2(t1.z*kk2.x - t1.w*kk2.y, t1.z*kk2.y + t1.w*kk2.x);
    }

    // ---- cross section (w0=L16 w1=L8 w2=R2 w3=R1 w4=L32 w5=L4 w6=L2 w7=L1) -
    const int a32 = (ln ^ 32) << 2;
    // wc_crx pairs (i -> i+4, then i+4 -> i)
    xcrx_l32<16>(s, ln, a32, sCS[16]);    // w0->w4
    xcrx_ll<32, 16>(s, ln, sCS[20]);      // w4->w0
    xcrx_ll<8, 4>(s, ln, sCS[17]);        // w1->w5
    xcrx_ll<4, 8>(s, ln, sCS[21]);        // w5->w1
    xcrx_rl<2, 2>(s, sCS[18]);            // w2->w6
    xcrx_lr<2, 2>(s, ln, sCS[22]);        // w6->w2
    xcrx_rl<1, 1>(s, sCS[19]);            // w3->w7
    xcrx_lr<1, 1>(s, ln, sCS[23]);        // w7->w3
    // wc_crx2 first half (disjoint pairs)
    xcrx_ll<16, 4>(s, ln, sCS[24]);       // w0->w5
    xcrx_ll<8, 2>(s, ln, sCS[25]);        // w1->w6
    xcrx_rl<2, 1>(s, sCS[26]);            // w2->w7
    xcrx_r32<1>(s, a32, sCS[27]);         // w3->w4
    // wc_crx2 second half (disjoint pairs)
    xcrx_ll<32, 8>(s, ln, sCS[28]);       // w4->w1
    xcrx_lr<4, 2>(s, ln, sCS[29]);        // w5->w2
    xcrx_lr<2, 1>(s, ln, sCS[30]);        // w6->w3
    xcrx_ll<1, 16>(s, ln, sCS[31]);       // w7->w0
    // CNOT pairs (w0,w4),(w1,w5) fused into one lane permutation:
    // new[a,b] = old[a^b, a] per pair  =>  src: L32'=L16, L16'=L16^L32,
    //                                         L8'=L8^L4, L4'=L8.
    {
        const int b5 = (ln >> 5) & 1, b4 = (ln >> 4) & 1;
        const int b3 = (ln >> 3) & 1, b2 = (ln >> 2) & 1;
        const int aperm = ((b4 << 5) | ((b4 ^ b5) << 4) | ((b3 ^ b2) << 3) |
                          (b3 << 2) | (ln & 3)) << 2;
#pragma unroll
        for (int r = 0; r < 4; r++) s[r] = bperm2(aperm, s[r]);
    }
    // CNOT pair (w2,w6): ctrl R2 tgt L2, then ctrl L2 tgt R2
    s[2] = lxor2<2>(s[2]); s[3] = lxor2<2>(s[3]);
    {
        const bool hi = (ln & 2) != 0;
        const float2 a0 = s[0], a2 = s[2]; s[0] = hi ? a2 : a0; s[2] = hi ? a0 : a2;
        const float2 a1 = s[1], a3 = s[3]; s[1] = hi ? a3 : a1; s[3] = hi ? a1 : a3;
    }
    // CNOT pair (w3,w7): ctrl R1 tgt L1, then ctrl L1 tgt R1
    s[1] = lxor2<1>(s[1]); s[3] = lxor2<1>(s[3]);
    {
        const bool hi = (ln & 1) != 0;
        const float2 a0 = s[0], a1 = s[1]; s[0] = hi ? a1 : a0; s[1] = hi ? a0 : a1;
        const float2 a2 = s[2], a3 = s[3]; s[2] = hi ? a3 : a2; s[3] = hi ? a2 : a3;
    }

    // ---- Heisenberg measurement -------------------------------------------
    float n2[4];
#pragma unroll
    for (int r = 0; r < 4; r++) n2[r] = s[r].x*s[r].x + s[r].y*s[r].y;
    float amp[4];
    {
        float z0, x0, z1, x1, z2, x2, z3, x3;
        measLn<16>(s, n2, ln, sMZ[0], sBX[0], z0, x0);   // w0
        measLn<8>(s, n2, ln, sMZ[1], sBX[1], z1, x1);    // w1
        measRR<2>(s, n2, sMZ[2], sBX[2], z2, x2);        // w2
        measRR<1>(s, n2, sMZ[3], sBX[3], z3, x3);        // w3
        z0 = red64(z0, a32); x0 = red64(x0, a32);
        z1 = red64(z1, a32); x1 = red64(x1, a32);
        z2 = red64(z2, a32); x2 = red64(x2, a32);
        z3 = red64(z3, a32); x3 = red64(x3, a32);
        amp[0] = sqrtf(z0*z0 + x0*x0);
        amp[1] = sqrtf(z1*z1 + x1*x1);
        amp[2] = sqrtf(z2*z2 + x2*x2);
        amp[3] = sqrtf(z3*z3 + x3*x3);
    }

    // ---- value circuit tail (valid in lanes 48-63; others compute garbage) -
#pragma unroll
    for (int i = 0; i < 4; i++) {
        const float e = __expf(2.f * amp[i]);
        const float th = 1.f - 2.f / (e + 1.f);
        const float ang = th * gates[i];
        float s_, c_;
        __sincosf(0.5f * ang, &s_, &c_);
        if (i == 0) srx<8>(A, c_, s_);
        if (i == 1) srx<4>(A, c_, s_);
        if (i == 2) srx<2>(A, c_, s_);
        if (i == 3) srx<1>(A, c_, s_);
    }
    scnot<8, 4>(A, l16); scnot<4, 2>(A, l16);
    scnot<2, 1>(A, l16); scnot<1, 8>(A, l16);

    // ---- value expectations + write ----------------------------------------
    const float vn2 = A.x*A.x + A.y*A.y;
    float oz[4], ox[4];
    {
        const float2 p8 = lxor2<8>(A), p4 = lxor2<4>(A),
                     p2 = lxor2<2>(A), p1 = lxor2<1>(A);
        oz[0] = red16((l16 & 8) ? -vn2 : vn2);
        oz[1] = red16((l16 & 4) ? -vn2 : vn2);
        oz[2] = red16((l16 & 2) ? -vn2 : vn2);
        oz[3] = red16((l16 & 1) ? -vn2 : vn2);
        ox[0] = red16(A.x*p8.x + A.y*p8.y);
        ox[1] = red16(A.x*p4.x + A.y*p4.y);
        ox[2] = red16(A.x*p2.x + A.y*p2.y);
        ox[3] = red16(A.x*p1.x + A.y*p1.y);
    }
    if (ln == 48) {   // first lane of the v-sim group
        float4* o = (float4*)(out + (size_t)b * 8);
        o[0] = make_float4(oz[0], oz[1], oz[2], oz[3]);
        o[1] = make_float4(ox[0], ox[1], ox[2], ox[3]);
    }
}

extern "C" void kernel_launch(void* const* d_in, const int* in_sizes, int n_in,
                              void* d_out, int out_size, void* d_ws, size_t ws_size,
                              hipStream_t stream) {
    (void)n_in; (void)out_size; (void)d_ws; (void)ws_size;
    const int B = in_sizes[0] / 96;
    const dim3 grid((B + 3) / 4), block(256);
    hipLaunchKernelGGL(qa_kernel, grid, block, 0, stream,
                       (const float*)d_in[0], (const float*)d_in[1],
                       (const float*)d_in[2], (const float*)d_in[3],
                       (const float*)d_in[4], (const float*)d_in[5],
                       (const float*)d_in[6], (const float*)d_in[7],
                       (const float*)d_in[8], (const float*)d_in[9],
                       (const float*)d_in[10], (const float*)d_in[11],
                       (const float*)d_in[12], (const float*)d_in[13],
                       (const float*)d_in[14], (const float*)d_in[15],
                       (float*)d_out, B);
}